// Round 8
// baseline (959.014 us; speedup 1.0000x reference)
//
#include <hip/hip_runtime.h>
#include <math.h>

// RecurrentSlotEncoder: B=16,K=16,N=1024,D=256,L=8
// Algebra: scores = (slots@Wqk) @ h^T      (no K-projection of h)
//          gi     = (attn@h)·rden @ WgiT + bgi, Wgi = W_ih@Wv  (no V-projection)
// R9 structure: 3 launches/step; partial-sum round-trips replaced by HW fp32
// atomics (unsafeAtomicAdd at L2):
//   attn (512 wgs): scores/Beta/den + attn@H accumulated straight into
//        upd_raw[b][l][d] / den_raw[b][l] (was par_av+par_den round-trip).
//   gru  (512 wgs = (b,kc16,role)): ONE barrier; stages 48KB weight slice,
//        computes gi/gh partials, atomicAdds into gsum[b][l][1536]
//        (was pg store + chainm 16-way combine: -37MB/step L2, -3 phases).
//   chainm (256 wgs = (b,l,ph)): gsum direct read -> GRU nonlin -> f1 -> x
//        -> LN -> s3 -> Qk-half; ph0 zeroes next-parity accumulators.
// Accumulators double-buffered by step parity; chainm(t) zeroes parity t+1
// (safe by launch order; chainm(15) re-zeroes parity 0 for graph replay;
// prologue also zeroes parity 0 after harness poison).

#define Bn 16
#define KK 16
#define Nn 1024
#define Dn 256
#define Ln 8

// workspace float offsets
#define OFF_WQK   0          // 256*256   Wqk[d][e]
#define OFF_BQK   65536      // 256
#define OFF_WGIT  65792      // 256*768   WgiT[e][jj] = sum_c Wih[jj][c]*Wv[c][e]
#define OFF_BGI   262400     // 768
#define OFF_WHHT  263168     // 256*768   WhhT[e][jj] = Whh[jj][e]
#define OFF_W1T   459776     // 256*256
#define OFF_W2T   525312     // 256*256
#define OFF_SLOTS 590848     // 2 x 128*256 ping-pong
#define OFF_QK    656384     // 128*256
#define OFF_ACC   689152     // 2 x (UPDR 32768 | DENR 128 | GSUM 196608)
#define ACC_STRIDE 229504
#define OFF_DENS  1148160    // [t*16+b][8] = 2048

__device__ __forceinline__ float sigmoidf_(float x) { return 1.f / (1.f + __expf(-x)); }

// Merged prologue: wg 0..256 = p1 (Wqk/bqk), 257..512 = p2 (WgiT/bgi),
// 513..832 = p3 transposes, 833..960 = init_slots, 961..1857 = zero parity-0
// accumulators (229504 floats).
__global__ __launch_bounds__(256) void prologue_kernel(
    const float* __restrict__ Wq, const float* __restrict__ bq,
    const float* __restrict__ Wk,
    const float* __restrict__ Wih, const float* __restrict__ bih,
    const float* __restrict__ Wv, const float* __restrict__ bv,
    const float* __restrict__ Whh, const float* __restrict__ W1,
    const float* __restrict__ W2,
    const float* __restrict__ eps, const float* __restrict__ mu,
    const float* __restrict__ lsig,
    float* __restrict__ Wqk, float* __restrict__ bqk,
    float* __restrict__ WgiT, float* __restrict__ bgi,
    float* __restrict__ WhhT, float* __restrict__ W1T, float* __restrict__ W2T,
    float* __restrict__ slots, float* __restrict__ acc0) {
  __shared__ float tile[32][33];
  int wg = blockIdx.x, tid = threadIdx.x;
  if (wg < 257) {
    int w = wg;
    if (w < 256) {
      float acc = 0.f;
#pragma unroll 8
      for (int a = 0; a < 256; ++a) acc += Wq[a * 256 + w] * Wk[a * 256 + tid];
      Wqk[w * 256 + tid] = acc;
    } else {
      float acc = 0.f;
#pragma unroll 8
      for (int a = 0; a < 256; ++a) acc += bq[a] * Wk[a * 256 + tid];
      bqk[tid] = acc;
    }
  } else if (wg < 513) {
    int d = wg - 257;
    float a0 = 0.f, a1 = 0.f, a2 = 0.f;
#pragma unroll 4
    for (int c = 0; c < 256; ++c) {
      float wv = Wv[c * 256 + d];  // wave-uniform
      a0 += Wih[tid * 256 + c] * wv;
      a1 += Wih[(tid + 256) * 256 + c] * wv;
      a2 += Wih[(tid + 512) * 256 + c] * wv;
    }
    WgiT[d * 768 + tid] = a0;
    WgiT[d * 768 + 256 + tid] = a1;
    WgiT[d * 768 + 512 + tid] = a2;
    if (d < 3) {
      int jj = d * 256 + tid;
      float s = bih[jj];
      for (int c = 0; c < 256; ++c) s += Wih[jj * 256 + c] * bv[c];
      bgi[jj] = s;
    }
  } else if (wg < 833) {
    int sub = wg - 513;
    const float* in; float* out; int R, C, tr, tc;
    if (sub < 192)      { in = Whh; out = WhhT; R = 768; C = 256; tr = sub >> 3; tc = sub & 7; }
    else if (sub < 256) { in = W1;  out = W1T;  R = 256; C = 256; sub -= 192; tr = sub >> 3; tc = sub & 7; }
    else                { in = W2;  out = W2T;  R = 256; C = 256; sub -= 256; tr = sub >> 3; tc = sub & 7; }
    int r = tid >> 5, c = tid & 31;
#pragma unroll
    for (int k = 0; k < 4; ++k)
      tile[r + 8 * k][c] = in[(tr * 32 + r + 8 * k) * C + tc * 32 + c];
    __syncthreads();
#pragma unroll
    for (int k = 0; k < 4; ++k)
      out[(tc * 32 + r + 8 * k) * R + tr * 32 + c] = tile[c][r + 8 * k];
  } else if (wg < 961) {
    int idx = (wg - 833) * 256 + tid;  // 0..32767
    int r = idx & 2047;
    slots[idx] = mu[r] + expf(lsig[r]) * eps[idx];
  } else {
    int idx = (wg - 961) * 256 + tid;  // 0..229631
    if (idx < ACC_STRIDE) acc0[idx] = 0.f;
  }
}

// Qk = slots @ Wqk + bqk (t=0 only)
__global__ __launch_bounds__(256) void qk0_kernel(
    const float* __restrict__ Wqk, const float* __restrict__ bqk,
    const float* __restrict__ slots, float* __restrict__ Qkout) {
  __shared__ float sl_s[2048];
  int j = blockIdx.x & 7, b = blockIdx.x >> 3, tid = threadIdx.x;
  for (int k = 0; k < 8; ++k) sl_s[tid + k * 256] = slots[b * 2048 + tid + k * 256];
  __syncthreads();
  int l = tid >> 5, ee = j * 32 + (tid & 31);
  float acc = bqk[ee];
#pragma unroll 8
  for (int d = 0; d < 256; ++d) acc += sl_s[l * 256 + d] * Wqk[d * 256 + ee];
  Qkout[b * 2048 + l * 256 + ee] = acc;
}

// Fused attention: wg = (tile32, b), grid (32,16). Stages 32 rows of H in LDS.
// Phase A reg-tiled (float4 LDS reads); eg-partials reduced in LDS.
// Phase B accumulates av and atomicAdds straight into upd_raw; den via atomic.
__global__ __launch_bounds__(256) void attn_kernel(
    const float* __restrict__ H, const float* __restrict__ Qk,
    float* __restrict__ beta_out, float* __restrict__ updr,
    float* __restrict__ denr, int t) {
  __shared__ float h_s[32 * 260];   // stride 260 floats (1040B, 16B-aligned)
  __shared__ float qk_s[8 * 260];
  __shared__ float red_a[8 * 256];  // [eg][l*32+row]
  __shared__ float es2[32 * 8];     // [row][l]
  __shared__ float red[256];        // [l*32+row] for den
  int tile = blockIdx.x, b = blockIdx.y, tid = threadIdx.x;
#pragma unroll
  for (int k = 0; k < 8; ++k) {
    int idx = tid + k * 256, l = idx >> 8, e = idx & 255;
    qk_s[l * 260 + e] = Qk[b * 2048 + idx];
  }
  const float4* src = (const float4*)(H + (((long)b * KK + t) * Nn + tile * 32) * Dn);
#pragma unroll
  for (int k = 0; k < 8; ++k) {
    int idx4 = tid + k * 256, r = idx4 >> 6, d4 = idx4 & 63;
    *(float4*)(&h_s[r * 260 + d4 * 4]) = src[idx4];
  }
  __syncthreads();
  // phase A
  {
    int eg = tid >> 5, lh = (tid >> 4) & 1, rq = tid & 15;
    float4 hA[8], hB[8];
    const float4* ha = (const float4*)(&h_s[(rq * 2) * 260 + eg * 32]);
    const float4* hb = (const float4*)(&h_s[(rq * 2 + 1) * 260 + eg * 32]);
#pragma unroll
    for (int i = 0; i < 8; ++i) { hA[i] = ha[i]; hB[i] = hb[i]; }
    float acc[4][2] = {{0.f, 0.f}, {0.f, 0.f}, {0.f, 0.f}, {0.f, 0.f}};
#pragma unroll
    for (int li = 0; li < 4; ++li) {
      const float4* qv = (const float4*)(&qk_s[(lh * 4 + li) * 260 + eg * 32]);
#pragma unroll
      for (int i = 0; i < 8; ++i) {
        float4 qq = qv[i];
        acc[li][0] += qq.x * hA[i].x + qq.y * hA[i].y + qq.z * hA[i].z + qq.w * hA[i].w;
        acc[li][1] += qq.x * hB[i].x + qq.y * hB[i].y + qq.z * hB[i].z + qq.w * hB[i].w;
      }
    }
#pragma unroll
    for (int li = 0; li < 4; ++li) {
      red_a[eg * 256 + (lh * 4 + li) * 32 + rq * 2] = acc[li][0];
      red_a[eg * 256 + (lh * 4 + li) * 32 + rq * 2 + 1] = acc[li][1];
    }
  }
  __syncthreads();
  // reduce eg-partials -> exp -> Beta + den staging
  {
    int l = tid >> 5, row = tid & 31;
    float a = 0.f;
#pragma unroll
    for (int eg = 0; eg < 8; ++eg) a += red_a[eg * 256 + l * 32 + row];
    float ev = __expf(a * 0.0625f);  // 1/sqrt(256); no max-sub (|s| small)
    es2[row * 8 + l] = ev;
    red[tid] = ev;
    beta_out[(((long)b * KK + t) * Ln + l) * Nn + tile * 32 + row] = ev;
  }
  __syncthreads();
  if (tid < 8) {
    float s = 0.f;
    for (int i = 0; i < 32; ++i) s += red[tid * 32 + i];
    unsafeAtomicAdd(&denr[b * 8 + tid], s);
  }
  // phase B: av[l] += e[row][l] * h[row][d=tid], then atomic into upd_raw
  float av[8] = {0.f, 0.f, 0.f, 0.f, 0.f, 0.f, 0.f, 0.f};
  for (int rr = 0; rr < 32; ++rr) {
    float hv = h_s[rr * 260 + tid];
    float4 ea = *(const float4*)(&es2[rr * 8]);
    float4 eb = *(const float4*)(&es2[rr * 8 + 4]);
    av[0] += ea.x * hv; av[1] += ea.y * hv; av[2] += ea.z * hv; av[3] += ea.w * hv;
    av[4] += eb.x * hv; av[5] += eb.y * hv; av[6] += eb.z * hv; av[7] += eb.w * hv;
  }
#pragma unroll
  for (int i = 0; i < 8; ++i)
    unsafeAtomicAdd(&updr[b * 2048 + i * 256 + tid], av[i]);
}

// GRU partial kernel, role-split: wg = (b, kc16, role), 512 wgs x 1024 thr.
// ONE barrier. role0: stage WgiT slice, x_s = upd_raw*1/den. role1: stage
// WhhT slice, x_s = slots slice. Compute 6 partials, atomicAdd into gsum.
__global__ __launch_bounds__(1024) void gru_kernel(
    const float* __restrict__ WgiT, const float* __restrict__ WhhT,
    const float* __restrict__ updr, const float* __restrict__ denr,
    const float* __restrict__ slots_cur, float* __restrict__ gsum,
    float* __restrict__ dens_all, int t) {
  __shared__ float w_s[16 * 768];  // 48KB staged slice
  __shared__ float x_s[128];       // upd (role0) or slots slice (role1)
  int wid = blockIdx.x;
  int b = wid & 15, kc = (wid >> 4) & 15, role = wid >> 8;
  int tid = threadIdx.x;

  const float4* wsrc = (const float4*)((role ? WhhT : WgiT) + kc * 12288);
  float4 wv0 = wsrc[tid], wv1 = wsrc[tid + 1024], wv2 = wsrc[tid + 2048];
  if (role == 0) {
    if (tid < 128) {
      int l = tid >> 4, e = tid & 15;
      float rd = 1.f / denr[b * 8 + l];
      x_s[tid] = updr[b * 2048 + l * 256 + kc * 16 + e] * rd;
    }
    if (kc == 0 && tid < 8) dens_all[(t * 16 + b) * 8 + tid] = 1.f / denr[b * 8 + tid];
  } else {
    if (tid < 128) x_s[tid] = slots_cur[b * 2048 + (tid >> 4) * 256 + kc * 16 + (tid & 15)];
  }
  ((float4*)w_s)[tid] = wv0;
  ((float4*)w_s)[tid + 1024] = wv1;
  ((float4*)w_s)[tid + 2048] = wv2;
  __syncthreads();

  // partials: thread = (l4 = tid>>8, cb = tid&255) covers rows {l4, l4+4}
  // and cols {cb, cb+256, cb+512} of its role's column block.
  int l4 = tid >> 8, cb = tid & 255;
  int off = role ? 768 : 0;
  float a0 = 0.f, a1 = 0.f, a2 = 0.f, a3 = 0.f, a4 = 0.f, a5 = 0.f;
#pragma unroll
  for (int e = 0; e < 16; ++e) {
    float u0 = x_s[l4 * 16 + e];
    float u1 = x_s[(l4 + 4) * 16 + e];
    float w0 = w_s[e * 768 + cb];
    float w1 = w_s[e * 768 + 256 + cb];
    float w2 = w_s[e * 768 + 512 + cb];
    a0 += u0 * w0; a1 += u0 * w1; a2 += u0 * w2;
    a3 += u1 * w0; a4 += u1 * w1; a5 += u1 * w2;
  }
  float* g0 = gsum + (b * 8 + l4) * 1536 + off;
  float* g1 = gsum + (b * 8 + l4 + 4) * 1536 + off;
  unsafeAtomicAdd(g0 + cb, a0);
  unsafeAtomicAdd(g0 + 256 + cb, a1);
  unsafeAtomicAdd(g0 + 512 + cb, a2);
  unsafeAtomicAdd(g1 + cb, a3);
  unsafeAtomicAdd(g1 + 256 + cb, a4);
  unsafeAtomicAdd(g1 + 512 + cb, a5);
}

// chainm: wg = (b, l, ph), 256 wgs x 1024 thr. gsum direct read -> GRU nonlin
// -> full f1 -> full x -> LN -> s3 (ph0 writes S/slots_nxt) -> Qk ph-half.
// ph0 zeroes next-parity accumulators (safe: nothing reads them this step).
__global__ __launch_bounds__(1024) void chainm_kernel(
    const float* __restrict__ gsum_c, float* __restrict__ updr_n,
    float* __restrict__ denr_n, float* __restrict__ gsum_n,
    const float* __restrict__ bgi, const float* __restrict__ bhh,
    const float* __restrict__ W1T, const float* __restrict__ b1,
    const float* __restrict__ W2T, const float* __restrict__ b2,
    const float* __restrict__ Wqk, const float* __restrict__ bqk,
    const float* __restrict__ ln_g, const float* __restrict__ ln_b,
    const float* __restrict__ slots_cur, float* __restrict__ slots_nxt,
    float* __restrict__ S, float* __restrict__ QkG, int t) {
  __shared__ float s2_s[256], f1s[256], s3_s[256];
  __shared__ float red4[1024];
  __shared__ float red8[128 * 9];
  __shared__ float lnr[8];
  int wid = blockIdx.x;
  int b = wid & 15, l = (wid >> 4) & 7, ph = wid >> 7;
  int tid = threadIdx.x, q = tid >> 8, c = tid & 255;

  // early-issue W1T group-0 loads (independent of everything below)
  float w1p[16];
  {
    const float* wp = W1T + (q * 64) * 256 + c;
#pragma unroll
    for (int i = 0; i < 16; ++i) w1p[i] = wp[i * 256];
  }

  // GRU nonlin from gsum directly (6 independent loads)
  if (tid < 256) {
    const float* gs = gsum_c + (b * 8 + l) * 1536;
    float gir = gs[c], giz = gs[256 + c], gin = gs[512 + c];
    float ghr = gs[768 + c], ghz = gs[1024 + c], ghn = gs[1280 + c];
    float r = sigmoidf_(gir + bgi[c] + ghr + bhh[c]);
    float z = sigmoidf_(giz + bgi[256 + c] + ghz + bhh[256 + c]);
    float n = tanhf(gin + bgi[512 + c] + r * (ghn + bhh[512 + c]));
    s2_s[c] = (1.f - z) * n + z * slots_cur[b * 2048 + l * 256 + c];
  }
  __syncthreads();
  // zero next-parity accumulators (ph0 only; nothing reads them this step)
  if (ph == 0) {
    float* gz = gsum_n + (b * 8 + l) * 1536;
    gz[tid] = 0.f;
    if (tid < 512) gz[1024 + tid] = 0.f;
    if (tid < 256) updr_n[b * 2048 + l * 256 + tid] = 0.f;
    if (tid == 0) denr_n[b * 8 + l] = 0.f;
  }
  // f1 full: thread (q,c), e = q*64..+64; group 0 from prefetch regs
  {
    const float* wp = W1T + (q * 64) * 256 + c;
    const float* sp = s2_s + q * 64;
    float acc = 0.f;
#pragma unroll
    for (int i = 0; i < 16; ++i) acc += sp[i] * w1p[i];
#pragma unroll
    for (int g = 1; g < 4; ++g) {
      float w[16];
#pragma unroll
      for (int i = 0; i < 16; ++i) w[i] = wp[(g * 16 + i) * 256];
#pragma unroll
      for (int i = 0; i < 16; ++i) acc += sp[g * 16 + i] * w[i];
    }
    red4[q * 256 + c] = acc;
  }
  __syncthreads();
  if (tid < 256)
    f1s[c] = fmaxf(red4[c] + red4[256 + c] + red4[512 + c] + red4[768 + c] + b1[c], 0.f);
  __syncthreads();
  // x full: thread (q,c), e = q*64..+64
  {
    const float* wp = W2T + (q * 64) * 256 + c;
    const float* fp = f1s + q * 64;
    float acc = 0.f;
#pragma unroll
    for (int g = 0; g < 4; ++g) {
      float w[16];
#pragma unroll
      for (int i = 0; i < 16; ++i) w[i] = wp[(g * 16 + i) * 256];
#pragma unroll
      for (int i = 0; i < 16; ++i) acc += fp[g * 16 + i] * w[i];
    }
    red4[q * 256 + c] = acc;
  }
  __syncthreads();
  if (tid < 256) {
    float x = red4[c] + red4[256 + c] + red4[512 + c] + red4[768 + c] + b2[c] + s2_s[c];
    s3_s[c] = x;  // temp: pre-LN value
    float sr = x, qr = x * x;
#pragma unroll
    for (int m = 1; m < 64; m <<= 1) { sr += __shfl_xor(sr, m); qr += __shfl_xor(qr, m); }
    if ((c & 63) == 0) { lnr[c >> 6] = sr; lnr[4 + (c >> 6)] = qr; }
  }
  __syncthreads();
  if (tid < 256) {
    float m = (lnr[0] + lnr[1] + lnr[2] + lnr[3]) * (1.f / 256.f);
    float v = (lnr[4] + lnr[5] + lnr[6] + lnr[7]) * (1.f / 256.f) - m * m;
    float s3 = (s3_s[c] - m) * rsqrtf(v + 1e-5f) * ln_g[c] + ln_b[c];
    s3_s[c] = s3;  // own element only
    if (ph == 0) {
      S[(((long)(b * 16) + t) * 8 + l) * 256 + c] = s3;
      slots_nxt[b * 2048 + l * 256 + c] = s3;
    }
  }
  __syncthreads();
  // Qk ph-half: thread (kc = tid>>7 in [0,8), cc = tid&127), e = kc*32..+32
  {
    int kc = tid >> 7, cc = tid & 127;
    const float* wp = Wqk + (kc * 32) * 256 + ph * 128 + cc;
    const float* sp = s3_s + kc * 32;
    float acc = 0.f;
#pragma unroll
    for (int g = 0; g < 2; ++g) {
      float w[16];
#pragma unroll
      for (int i = 0; i < 16; ++i) w[i] = wp[(g * 16 + i) * 256];
#pragma unroll
      for (int i = 0; i < 16; ++i) acc += sp[g * 16 + i] * w[i];
    }
    red8[cc * 9 + kc] = acc;
  }
  __syncthreads();
  if (tid < 128) {
    float a = bqk[ph * 128 + tid];
#pragma unroll
    for (int kc = 0; kc < 8; ++kc) a += red8[tid * 9 + kc];
    QkG[b * 2048 + l * 256 + ph * 128 + tid] = a;
  }
}

// Post-pass: Beta[b,t,l,:] *= dens_all[t*16+b][l] for all 16 steps at once.
__global__ __launch_bounds__(1024) void beta_norm_kernel(
    const float* __restrict__ dens_all, float* __restrict__ Beta) {
  int wid = blockIdx.x;
  int b = wid >> 4, t = wid & 15;
  int tid = threadIdx.x;
  long base = (((long)b * 16) + t) * 8192;
#pragma unroll
  for (int i = 0; i < 8; ++i) {
    int idx = i * 1024 + tid;
    int l = idx >> 10;
    Beta[base + idx] *= dens_all[(t * 16 + b) * 8 + l];
  }
}

extern "C" void kernel_launch(void* const* d_in, const int* in_sizes, int n_in,
                              void* d_out, int out_size, void* d_ws, size_t ws_size,
                              hipStream_t stream) {
  const float* H    = (const float*)d_in[0];
  const float* eps  = (const float*)d_in[1];
  const float* mu   = (const float*)d_in[2];
  const float* lsig = (const float*)d_in[3];
  const float* Wq   = (const float*)d_in[4];
  const float* bq   = (const float*)d_in[5];
  const float* Wk   = (const float*)d_in[6];
  // d_in[7] = bk: constant per softmax row -> drops out
  const float* Wv   = (const float*)d_in[8];
  const float* bv   = (const float*)d_in[9];
  const float* Wih  = (const float*)d_in[10];
  const float* bih  = (const float*)d_in[11];
  const float* Whh  = (const float*)d_in[12];
  const float* bhh  = (const float*)d_in[13];
  const float* W1   = (const float*)d_in[14];
  const float* b1   = (const float*)d_in[15];
  const float* W2   = (const float*)d_in[16];
  const float* b2   = (const float*)d_in[17];
  const float* ln_g = (const float*)d_in[18];
  const float* ln_b = (const float*)d_in[19];

  float* out = (float*)d_out;
  float* S    = out;                            // [B,K,L,D]
  float* Beta = out + (long)Bn * KK * Ln * Dn;  // [B,K,L,N]

  float* ws = (float*)d_ws;
  float* Wqk    = ws + OFF_WQK;
  float* bqk    = ws + OFF_BQK;
  float* WgiT   = ws + OFF_WGIT;
  float* bgi    = ws + OFF_BGI;
  float* WhhT   = ws + OFF_WHHT;
  float* W1T    = ws + OFF_W1T;
  float* W2T    = ws + OFF_W2T;
  float* slots0 = ws + OFF_SLOTS;   // ping-pong pair
  float* Qk     = ws + OFF_QK;
  float* acc    = ws + OFF_ACC;     // parity-buffered accumulators
  float* dens   = ws + OFF_DENS;

  prologue_kernel<<<1858, 256, 0, stream>>>(Wq, bq, Wk, Wih, bih, Wv, bv, Whh, W1, W2,
                                            eps, mu, lsig,
                                            Wqk, bqk, WgiT, bgi, WhhT, W1T, W2T,
                                            slots0, acc);
  qk0_kernel<<<128, 256, 0, stream>>>(Wqk, bqk, slots0, Qk);

  for (int t = 0; t < KK; ++t) {
    float* scur = slots0 + (t & 1) * 32768;
    float* snxt = slots0 + ((t + 1) & 1) * 32768;
    float* accc = acc + (t & 1) * ACC_STRIDE;
    float* accn = acc + ((t + 1) & 1) * ACC_STRIDE;
    float* updr_c = accc;             float* updr_n = accn;
    float* denr_c = accc + 32768;     float* denr_n = accn + 32768;
    float* gsum_c = accc + 32896;     float* gsum_n = accn + 32896;
    attn_kernel<<<dim3(32, 16), 256, 0, stream>>>(H, Qk, Beta, updr_c, denr_c, t);
    gru_kernel<<<512, 1024, 0, stream>>>(WgiT, WhhT, updr_c, denr_c, scur,
                                         gsum_c, dens, t);
    chainm_kernel<<<256, 1024, 0, stream>>>(gsum_c, updr_n, denr_n, gsum_n,
                                            bgi, bhh, W1T, b1, W2T, b2,
                                            Wqk, bqk, ln_g, ln_b, scur, snxt,
                                            S, Qk, t);
  }
  beta_norm_kernel<<<256, 1024, 0, stream>>>(dens, Beta);
}